// Round 3
// baseline (614.751 us; speedup 1.0000x reference)
//
#include <hip/hip_runtime.h>

// ---------------------------------------------------------------------------
// SageCox: 4-layer GraphSAGE (mean aggr), N=100000 nodes, E=640000 edges.
// Per layer: out = mean_neigh(x) @ Wl + bl + x @ Wr
// Restructured: p = x@Wl ; acc = x@Wr + bl ; acc[d] += invdeg[d]*sum p[src].
// Aggregation via CSR gather (no float atomics). Proj = register-tiled GEMM:
// block = 64 rows x CWALL cols (all cols, x read once), thread = 4 rows x
// 4*NQ cols, k blocked by 4 (ds_read_b128 from padded LDS tile).
// Wcat = [Wl | pad | Wr | pad], k-rows zero-padded to DINP (mult of 4).
// ---------------------------------------------------------------------------

#define NNODES 100000
#define NEDGES 640000

// ---- CSR build ------------------------------------------------------------

__global__ void hist_kernel(const int* __restrict__ edst, int* __restrict__ deg, int E) {
    int i = blockIdx.x * blockDim.x + threadIdx.x;
    if (i < E) atomicAdd(&deg[edst[i]], 1);
}

__global__ void scanA_kernel(const int* __restrict__ deg, int* __restrict__ bsum, int N) {
    __shared__ int s[256];
    int i = blockIdx.x * 256 + threadIdx.x;
    s[threadIdx.x] = (i < N) ? deg[i] : 0;
    __syncthreads();
    for (int off = 128; off > 0; off >>= 1) {
        if (threadIdx.x < off) s[threadIdx.x] += s[threadIdx.x + off];
        __syncthreads();
    }
    if (threadIdx.x == 0) bsum[blockIdx.x] = s[0];
}

__global__ void scanB_kernel(const int* __restrict__ bsum, int* __restrict__ bpre, int nb) {
    __shared__ int s[512];
    int t = threadIdx.x;
    int v = (t < nb) ? bsum[t] : 0;
    s[t] = v;
    __syncthreads();
    for (int off = 1; off < 512; off <<= 1) {
        int add = (t >= off) ? s[t - off] : 0;
        __syncthreads();
        s[t] += add;
        __syncthreads();
    }
    if (t < nb) bpre[t] = s[t] - v;  // exclusive
}

__global__ void scanC_kernel(const int* __restrict__ deg, const int* __restrict__ bpre,
                             int* __restrict__ rowptr, int* __restrict__ cursor, int N, int E) {
    __shared__ int s[256];
    int t = threadIdx.x;
    int i = blockIdx.x * 256 + t;
    int v = (i < N) ? deg[i] : 0;
    s[t] = v;
    __syncthreads();
    for (int off = 1; off < 256; off <<= 1) {
        int add = (t >= off) ? s[t - off] : 0;
        __syncthreads();
        s[t] += add;
        __syncthreads();
    }
    if (i < N) {
        int excl = bpre[blockIdx.x] + s[t] - v;
        rowptr[i] = excl;
        cursor[i] = excl;
        if (i == N - 1) rowptr[N] = E;
    }
}

__global__ void fill_kernel(const int* __restrict__ esrc, const int* __restrict__ edst,
                            int* __restrict__ cursor, int* __restrict__ csr, int E) {
    int i = blockIdx.x * blockDim.x + threadIdx.x;
    if (i < E) {
        int pos = atomicAdd(&cursor[edst[i]], 1);
        csr[pos] = esrc[i];
    }
}

// ---- weight pack ----------------------------------------------------------
// Wcat[k][c], k < DINP (zero for k >= DIN): c<DOUT -> Wl, DOUTP<=c<DOUTP+DOUT -> Wr

__global__ void pack_kernel(const float* __restrict__ Wl, const float* __restrict__ Wr,
                            float* __restrict__ Wcat, int DIN, int DINP, int DOUT,
                            int DOUTP, int CWALL) {
    int idx = blockIdx.x * blockDim.x + threadIdx.x;
    int tot = DINP * CWALL;
    if (idx >= tot) return;
    int k = idx / CWALL, c = idx - k * CWALL;
    float v = 0.0f;
    if (k < DIN) {
        if (c < DOUT) v = Wl[k * DOUT + c];
        else if (c >= DOUTP && c < DOUTP + DOUT) v = Wr[k * DOUT + (c - DOUTP)];
    }
    Wcat[idx] = v;
}

// ---- projection: p = x@Wl, out = x@Wr + bl --------------------------------

template <int DIN, int DINP, int DOUT, int DOUTP, int CWALL>
__global__ void __launch_bounds__(256)
proj_kernel(const float* __restrict__ x, const float* __restrict__ Wcat,
            const float* __restrict__ bl, float* __restrict__ p,
            float* __restrict__ out, int N) {
    constexpr int NQ = CWALL / 64;      // col-quads per thread
    constexpr int STR = DINP + 4;       // LDS row stride (mult of 4, odd banks)
    __shared__ float xs[64 * STR];
    const int row0 = blockIdx.x * 64;

    for (int idx = threadIdx.x; idx < 64 * DINP; idx += 256) {
        const int r = idx / DINP, k = idx - r * DINP;
        const int row = row0 + r;
        float v = 0.0f;
        if (row < N && k < DIN) v = x[(size_t)row * DIN + k];
        xs[r * STR + k] = v;
    }
    __syncthreads();

    const int cq = threadIdx.x & 15;    // 16 col-quads of 4 cols, repeated NQ x
    const int rq = threadIdx.x >> 4;    // 16 row-groups of 4 rows
    const int c0 = cq * 4;
    const int r0 = rq * 4;

    float acc[4][NQ * 4] = {};

    for (int k0 = 0; k0 < DINP; k0 += 4) {
        float xv[4][4];
#pragma unroll
        for (int j = 0; j < 4; ++j) {
            const float4 t = *(const float4*)&xs[(r0 + j) * STR + k0];
            xv[j][0] = t.x; xv[j][1] = t.y; xv[j][2] = t.z; xv[j][3] = t.w;
        }
#pragma unroll
        for (int kk = 0; kk < 4; ++kk) {
            const float* __restrict__ wrow = Wcat + (size_t)(k0 + kk) * CWALL + c0;
#pragma unroll
            for (int q = 0; q < NQ; ++q) {
                const float4 w = *(const float4*)(wrow + q * 64);
#pragma unroll
                for (int j = 0; j < 4; ++j) {
                    acc[j][q * 4 + 0] = fmaf(xv[j][kk], w.x, acc[j][q * 4 + 0]);
                    acc[j][q * 4 + 1] = fmaf(xv[j][kk], w.y, acc[j][q * 4 + 1]);
                    acc[j][q * 4 + 2] = fmaf(xv[j][kk], w.z, acc[j][q * 4 + 2]);
                    acc[j][q * 4 + 3] = fmaf(xv[j][kk], w.w, acc[j][q * 4 + 3]);
                }
            }
        }
    }

#pragma unroll
    for (int j = 0; j < 4; ++j) {
        const int row = row0 + r0 + j;
        if (row >= N) continue;
#pragma unroll
        for (int q = 0; q < NQ; ++q) {
#pragma unroll
            for (int i = 0; i < 4; ++i) {
                const int c = c0 + q * 64 + i;
                if (c < DOUT) {
                    p[(size_t)row * DOUT + c] = acc[j][q * 4 + i];
                } else if (c >= DOUTP && c < DOUTP + DOUT) {
                    const int co = c - DOUTP;
                    out[(size_t)row * DOUT + co] = acc[j][q * 4 + i] + bl[co];
                }
            }
        }
    }
}

// ---- gather aggregation: out[d] += invdeg * sum_{s in N(d)} p[s] ----------

template <int DOUT>
__global__ void __launch_bounds__(256)
gather_kernel(const int* __restrict__ rowptr, const int* __restrict__ csr,
              const float* __restrict__ p, float* __restrict__ out, int N) {
    const int node = (blockIdx.x * 256 + threadIdx.x) >> 6;
    const int lane = threadIdx.x & 63;
    if (node >= N) return;
    const int beg = rowptr[node];
    const int end = rowptr[node + 1];
    const float inv = 1.0f / (float)max(end - beg, 1);
    float a0 = 0.0f, a1 = 0.0f;
    for (int j = beg; j < end; ++j) {
        const int s = csr[j];
        const float* __restrict__ pr = p + (size_t)s * DOUT;
        if (lane < DOUT) a0 += pr[lane];
        if (DOUT > 64 && lane + 64 < DOUT) a1 += pr[lane + 64];
    }
    if (lane < DOUT) out[(size_t)node * DOUT + lane] += inv * a0;
    if (DOUT > 64 && lane + 64 < DOUT) out[(size_t)node * DOUT + lane + 64] += inv * a1;
}

__global__ void gather1_kernel(const int* __restrict__ rowptr, const int* __restrict__ csr,
                               const float* __restrict__ p, float* __restrict__ out, int N) {
    const int node = blockIdx.x * blockDim.x + threadIdx.x;
    if (node >= N) return;
    const int beg = rowptr[node];
    const int end = rowptr[node + 1];
    const float inv = 1.0f / (float)max(end - beg, 1);
    float a = 0.0f;
    for (int j = beg; j < end; ++j) a += p[csr[j]];
    out[node] += inv * a;
}

// ---- layer 3 (28 -> 1) GEMV ----------------------------------------------

__global__ void __launch_bounds__(256)
gemv3_kernel(const float* __restrict__ x, const float* __restrict__ Wl,
             const float* __restrict__ bl, const float* __restrict__ Wr,
             float* __restrict__ p, float* __restrict__ out, int N) {
    __shared__ float xs[256 * 28];
    const int row0 = blockIdx.x * 256;
    for (int idx = threadIdx.x; idx < 256 * 28; idx += 256) {
        int r = row0 + idx / 28;
        xs[idx] = (r < N) ? x[(size_t)row0 * 28 + idx] : 0.0f;
    }
    __syncthreads();
    const int row = row0 + threadIdx.x;
    if (row >= N) return;
    float sl = 0.0f, sr = 0.0f;
#pragma unroll
    for (int k = 0; k < 28; ++k) {
        const float xv = xs[threadIdx.x * 28 + k];
        sl = fmaf(xv, Wl[k], sl);
        sr = fmaf(xv, Wr[k], sr);
    }
    p[row] = sl;
    out[row] = sr + bl[0];
}

// ---------------------------------------------------------------------------

extern "C" void kernel_launch(void* const* d_in, const int* in_sizes, int n_in,
                              void* d_out, int out_size, void* d_ws, size_t ws_size,
                              hipStream_t stream) {
    const float* x  = (const float*)d_in[0];
    const int*   ei = (const int*)d_in[1];
    const int N = NNODES;
    const int E = NEDGES;
    const int* esrc = ei;
    const int* edst = ei + E;

    const float* Wl[4] = {(const float*)d_in[2], (const float*)d_in[5],
                          (const float*)d_in[8], (const float*)d_in[11]};
    const float* bl[4] = {(const float*)d_in[3], (const float*)d_in[6],
                          (const float*)d_in[9], (const float*)d_in[12]};
    const float* Wr[4] = {(const float*)d_in[4], (const float*)d_in[7],
                          (const float*)d_in[10], (const float*)d_in[13]};

    // workspace layout (floats), 16B-aligned chunks
    float* ws = (float*)d_ws;
    size_t off = 0;
    auto alloc = [&](size_t n) { float* r = ws + off; off += (n + 3) & ~(size_t)3; return r; };
    float* Wc0  = alloc(128 * 192);
    float* Wc1  = alloc(88 * 128);
    float* Wc2  = alloc(56 * 64);
    float* pbuf = alloc((size_t)N * 85);
    float* bufA = alloc((size_t)N * 85);
    float* bufB = alloc((size_t)N * 56);
    int* degi   = (int*)alloc(N);
    int* rowptr = (int*)alloc(N + 1);
    int* cursor = (int*)alloc(N);
    int* csr    = (int*)alloc(E);
    int* bsum   = (int*)alloc(512);
    int* bpre   = (int*)alloc(512);

    const int nb = (N + 255) / 256;  // 391

    // CSR build
    hipMemsetAsync(degi, 0, (size_t)N * sizeof(int), stream);
    hist_kernel<<<(E + 255) / 256, 256, 0, stream>>>(edst, degi, E);
    scanA_kernel<<<nb, 256, 0, stream>>>(degi, bsum, N);
    scanB_kernel<<<1, 512, 0, stream>>>(bsum, bpre, nb);
    scanC_kernel<<<nb, 256, 0, stream>>>(degi, bpre, rowptr, cursor, N, E);
    fill_kernel<<<(E + 255) / 256, 256, 0, stream>>>(esrc, edst, cursor, csr, E);

    // weight packs
    pack_kernel<<<(128 * 192 + 255) / 256, 256, 0, stream>>>(Wl[0], Wr[0], Wc0, 128, 128, 85, 88, 192);
    pack_kernel<<<(88 * 128 + 255) / 256, 256, 0, stream>>>(Wl[1], Wr[1], Wc1, 85, 88, 56, 64, 128);
    pack_kernel<<<(56 * 64 + 255) / 256, 256, 0, stream>>>(Wl[2], Wr[2], Wc2, 56, 56, 28, 32, 64);

    const int rowTiles = (N + 63) / 64;  // 1563

    // Layer 0: 128 -> 85
    proj_kernel<128, 128, 85, 88, 192><<<rowTiles, 256, 0, stream>>>(
        x, Wc0, bl[0], pbuf, bufA, N);
    gather_kernel<85><<<(N + 3) / 4, 256, 0, stream>>>(rowptr, csr, pbuf, bufA, N);

    // Layer 1: 85 -> 56
    proj_kernel<85, 88, 56, 64, 128><<<rowTiles, 256, 0, stream>>>(
        bufA, Wc1, bl[1], pbuf, bufB, N);
    gather_kernel<56><<<(N + 3) / 4, 256, 0, stream>>>(rowptr, csr, pbuf, bufB, N);

    // Layer 2: 56 -> 28
    proj_kernel<56, 56, 28, 32, 64><<<rowTiles, 256, 0, stream>>>(
        bufB, Wc2, bl[2], pbuf, bufA, N);
    gather_kernel<28><<<(N + 3) / 4, 256, 0, stream>>>(rowptr, csr, pbuf, bufA, N);

    // Layer 3: 28 -> 1
    gemv3_kernel<<<(N + 255) / 256, 256, 0, stream>>>(
        bufA, Wl[3], bl[3], Wr[3], pbuf, (float*)d_out, N);
    gather1_kernel<<<(N + 255) / 256, 256, 0, stream>>>(
        rowptr, csr, pbuf, (float*)d_out, N);
}

// Round 4
// 570.303 us; speedup vs baseline: 1.0779x; 1.0779x over previous
//
#include <hip/hip_runtime.h>

// ---------------------------------------------------------------------------
// SageCox: 4-layer GraphSAGE (mean aggr), N=100000 nodes, E=640000 edges.
// Per layer: out = mean_neigh(x) @ Wl + bl + x @ Wr
// Restructured: p = x@Wl ; acc = x@Wr + bl ; acc[d] += invdeg[d]*sum p[src].
// Aggregation via CSR gather (no float atomics).
// Proj: register-only GEMM, no LDS. Thread=(cq,rq): 4 rows x 4*NQ cols.
// x loads are wave-broadcast (16 lanes share rq -> same float4); W loads are
// 4-way broadcast contiguous 256B/wave. Wcat = [Wl|pad|Wr|pad] zero-padded
// to DINP k-rows so padded-k reads multiply 0. Intermediate buffers use
// 16B-aligned row strides (85 -> 88).
// ---------------------------------------------------------------------------

#define NNODES 100000
#define NEDGES 640000

// ---- CSR build ------------------------------------------------------------

__global__ void hist_kernel(const int* __restrict__ edst, int* __restrict__ deg, int E) {
    int i = blockIdx.x * blockDim.x + threadIdx.x;
    if (i < E) atomicAdd(&deg[edst[i]], 1);
}

__global__ void scanA_kernel(const int* __restrict__ deg, int* __restrict__ bsum, int N) {
    __shared__ int s[256];
    int i = blockIdx.x * 256 + threadIdx.x;
    s[threadIdx.x] = (i < N) ? deg[i] : 0;
    __syncthreads();
    for (int off = 128; off > 0; off >>= 1) {
        if (threadIdx.x < off) s[threadIdx.x] += s[threadIdx.x + off];
        __syncthreads();
    }
    if (threadIdx.x == 0) bsum[blockIdx.x] = s[0];
}

__global__ void scanB_kernel(const int* __restrict__ bsum, int* __restrict__ bpre, int nb) {
    __shared__ int s[512];
    int t = threadIdx.x;
    int v = (t < nb) ? bsum[t] : 0;
    s[t] = v;
    __syncthreads();
    for (int off = 1; off < 512; off <<= 1) {
        int add = (t >= off) ? s[t - off] : 0;
        __syncthreads();
        s[t] += add;
        __syncthreads();
    }
    if (t < nb) bpre[t] = s[t] - v;  // exclusive
}

__global__ void scanC_kernel(const int* __restrict__ deg, const int* __restrict__ bpre,
                             int* __restrict__ rowptr, int* __restrict__ cursor, int N, int E) {
    __shared__ int s[256];
    int t = threadIdx.x;
    int i = blockIdx.x * 256 + t;
    int v = (i < N) ? deg[i] : 0;
    s[t] = v;
    __syncthreads();
    for (int off = 1; off < 256; off <<= 1) {
        int add = (t >= off) ? s[t - off] : 0;
        __syncthreads();
        s[t] += add;
        __syncthreads();
    }
    if (i < N) {
        int excl = bpre[blockIdx.x] + s[t] - v;
        rowptr[i] = excl;
        cursor[i] = excl;
        if (i == N - 1) rowptr[N] = E;
    }
}

__global__ void fill_kernel(const int* __restrict__ esrc, const int* __restrict__ edst,
                            int* __restrict__ cursor, int* __restrict__ csr, int E) {
    int i = blockIdx.x * blockDim.x + threadIdx.x;
    if (i < E) {
        int pos = atomicAdd(&cursor[edst[i]], 1);
        csr[pos] = esrc[i];
    }
}

// ---- weight pack ----------------------------------------------------------

__global__ void pack_kernel(const float* __restrict__ Wl, const float* __restrict__ Wr,
                            float* __restrict__ Wcat, int DIN, int DINP, int DOUT,
                            int DOUTP, int CWALL) {
    int idx = blockIdx.x * blockDim.x + threadIdx.x;
    int tot = DINP * CWALL;
    if (idx >= tot) return;
    int k = idx / CWALL, c = idx - k * CWALL;
    float v = 0.0f;
    if (k < DIN) {
        if (c < DOUT) v = Wl[k * DOUT + c];
        else if (c >= DOUTP && c < DOUTP + DOUT) v = Wr[k * DOUT + (c - DOUTP)];
    }
    Wcat[idx] = v;
}

// ---- projection: p = x@Wl, out = x@Wr + bl (register-only) ----------------
// SIN: input row stride (>= DINP, both mult of 4). SOUT: output row stride.

template <int DINP, int SIN, int DOUT, int SOUT, int DOUTP, int CWALL>
__global__ void __launch_bounds__(256, 3)
proj_kernel(const float* __restrict__ x, const float* __restrict__ Wcat,
            const float* __restrict__ bl, float* __restrict__ p,
            float* __restrict__ out, int N) {
    constexpr int NQ = CWALL / 64;
    const int row0 = blockIdx.x * 64;
    const int cq = threadIdx.x & 15;
    const int rq = threadIdx.x >> 4;
    const int c0 = cq * 4;

    const float* __restrict__ xr[4];
#pragma unroll
    for (int j = 0; j < 4; ++j) {
        int r = row0 + rq * 4 + j;
        if (r >= N) r = N - 1;           // clamp: results discarded at store
        xr[j] = x + (size_t)r * SIN;
    }
    const float* __restrict__ wbase = Wcat + c0;

    float acc[4][NQ * 4] = {};

    for (int k0 = 0; k0 < DINP; k0 += 4) {
        float xb[4][4];
#pragma unroll
        for (int j = 0; j < 4; ++j) {
            const float4 t = *(const float4*)(xr[j] + k0);
            xb[j][0] = t.x; xb[j][1] = t.y; xb[j][2] = t.z; xb[j][3] = t.w;
        }
        float4 wv[4][NQ];
#pragma unroll
        for (int kk = 0; kk < 4; ++kk)
#pragma unroll
            for (int q = 0; q < NQ; ++q)
                wv[kk][q] = *(const float4*)(wbase + (size_t)(k0 + kk) * CWALL + q * 64);

#pragma unroll
        for (int kk = 0; kk < 4; ++kk)
#pragma unroll
            for (int q = 0; q < NQ; ++q)
#pragma unroll
                for (int j = 0; j < 4; ++j) {
                    acc[j][q * 4 + 0] = fmaf(xb[j][kk], wv[kk][q].x, acc[j][q * 4 + 0]);
                    acc[j][q * 4 + 1] = fmaf(xb[j][kk], wv[kk][q].y, acc[j][q * 4 + 1]);
                    acc[j][q * 4 + 2] = fmaf(xb[j][kk], wv[kk][q].z, acc[j][q * 4 + 2]);
                    acc[j][q * 4 + 3] = fmaf(xb[j][kk], wv[kk][q].w, acc[j][q * 4 + 3]);
                }
    }

#pragma unroll
    for (int j = 0; j < 4; ++j) {
        const int row = row0 + rq * 4 + j;
        if (row >= N) continue;
#pragma unroll
        for (int q = 0; q < NQ; ++q)
#pragma unroll
            for (int i = 0; i < 4; ++i) {
                const int c = c0 + q * 64 + i;
                if (c < DOUT) {
                    p[(size_t)row * SOUT + c] = acc[j][q * 4 + i];
                } else if (c >= DOUTP && c < DOUTP + DOUT) {
                    const int co = c - DOUTP;
                    out[(size_t)row * SOUT + co] = acc[j][q * 4 + i] + bl[co];
                }
            }
    }
}

// ---- gather aggregation: out[d] += invdeg * sum_{s in N(d)} p[s] ----------

template <int DOUT, int SP>
__global__ void __launch_bounds__(256)
gather_kernel(const int* __restrict__ rowptr, const int* __restrict__ csr,
              const float* __restrict__ p, float* __restrict__ out, int N) {
    const int node = (blockIdx.x * 256 + threadIdx.x) >> 6;
    const int lane = threadIdx.x & 63;
    if (node >= N) return;
    const int beg = rowptr[node];
    const int end = rowptr[node + 1];
    const float inv = 1.0f / (float)max(end - beg, 1);
    float a0 = 0.0f, a1 = 0.0f;
    for (int j = beg; j < end; ++j) {
        const int s = csr[j];
        const float* __restrict__ pr = p + (size_t)s * SP;
        if (lane < DOUT) a0 += pr[lane];
        if (DOUT > 64 && lane + 64 < DOUT) a1 += pr[lane + 64];
    }
    if (lane < DOUT) out[(size_t)node * SP + lane] += inv * a0;
    if (DOUT > 64 && lane + 64 < DOUT) out[(size_t)node * SP + lane + 64] += inv * a1;
}

__global__ void gather1_kernel(const int* __restrict__ rowptr, const int* __restrict__ csr,
                               const float* __restrict__ p, float* __restrict__ out, int N) {
    const int node = blockIdx.x * blockDim.x + threadIdx.x;
    if (node >= N) return;
    const int beg = rowptr[node];
    const int end = rowptr[node + 1];
    const float inv = 1.0f / (float)max(end - beg, 1);
    float a = 0.0f;
    for (int j = beg; j < end; ++j) a += p[csr[j]];
    out[node] += inv * a;
}

// ---- layer 3 (28 -> 1) GEMV ----------------------------------------------

__global__ void __launch_bounds__(256)
gemv3_kernel(const float* __restrict__ x, const float* __restrict__ Wl,
             const float* __restrict__ bl, const float* __restrict__ Wr,
             float* __restrict__ p, float* __restrict__ out, int N) {
    const int row = blockIdx.x * 256 + threadIdx.x;
    if (row >= N) return;
    const float* __restrict__ xrow = x + (size_t)row * 28;
    float sl = 0.0f, sr = 0.0f;
#pragma unroll
    for (int k = 0; k < 28; ++k) {
        const float xv = xrow[k];
        sl = fmaf(xv, Wl[k], sl);
        sr = fmaf(xv, Wr[k], sr);
    }
    p[row] = sl;
    out[row] = sr + bl[0];
}

// ---------------------------------------------------------------------------

extern "C" void kernel_launch(void* const* d_in, const int* in_sizes, int n_in,
                              void* d_out, int out_size, void* d_ws, size_t ws_size,
                              hipStream_t stream) {
    const float* x  = (const float*)d_in[0];
    const int*   ei = (const int*)d_in[1];
    const int N = NNODES;
    const int E = NEDGES;
    const int* esrc = ei;
    const int* edst = ei + E;

    const float* Wl[4] = {(const float*)d_in[2], (const float*)d_in[5],
                          (const float*)d_in[8], (const float*)d_in[11]};
    const float* bl[4] = {(const float*)d_in[3], (const float*)d_in[6],
                          (const float*)d_in[9], (const float*)d_in[12]};
    const float* Wr[4] = {(const float*)d_in[4], (const float*)d_in[7],
                          (const float*)d_in[10], (const float*)d_in[13]};

    // workspace layout (floats), 16B-aligned chunks
    float* ws = (float*)d_ws;
    size_t off = 0;
    auto alloc = [&](size_t n) { float* r = ws + off; off += (n + 3) & ~(size_t)3; return r; };
    float* Wc0  = alloc(128 * 192);
    float* Wc1  = alloc(88 * 128);
    float* Wc2  = alloc(56 * 64);
    float* pbuf = alloc((size_t)N * 88);   // stride-88 (L0) / 56 (L1) / 28 (L2)
    float* bufA = alloc((size_t)N * 88);   // L0/L2 acc
    float* bufB = alloc((size_t)N * 56);   // L1 acc
    int* degi   = (int*)alloc(N);
    int* rowptr = (int*)alloc(N + 1);
    int* cursor = (int*)alloc(N);
    int* csr    = (int*)alloc(E);
    int* bsum   = (int*)alloc(512);
    int* bpre   = (int*)alloc(512);

    const int nb = (N + 255) / 256;  // 391

    // CSR build
    hipMemsetAsync(degi, 0, (size_t)N * sizeof(int), stream);
    hist_kernel<<<(E + 255) / 256, 256, 0, stream>>>(edst, degi, E);
    scanA_kernel<<<nb, 256, 0, stream>>>(degi, bsum, N);
    scanB_kernel<<<1, 512, 0, stream>>>(bsum, bpre, nb);
    scanC_kernel<<<nb, 256, 0, stream>>>(degi, bpre, rowptr, cursor, N, E);
    fill_kernel<<<(E + 255) / 256, 256, 0, stream>>>(esrc, edst, cursor, csr, E);

    // weight packs
    pack_kernel<<<(128 * 192 + 255) / 256, 256, 0, stream>>>(Wl[0], Wr[0], Wc0, 128, 128, 85, 88, 192);
    pack_kernel<<<(88 * 128 + 255) / 256, 256, 0, stream>>>(Wl[1], Wr[1], Wc1, 85, 88, 56, 64, 128);
    pack_kernel<<<(56 * 64 + 255) / 256, 256, 0, stream>>>(Wl[2], Wr[2], Wc2, 56, 56, 28, 32, 64);

    const int rowTiles = (N + 63) / 64;  // 1563

    // Layer 0: 128 -> 85 (strides: in 128, out 88)
    proj_kernel<128, 128, 85, 88, 88, 192><<<rowTiles, 256, 0, stream>>>(
        x, Wc0, bl[0], pbuf, bufA, N);
    gather_kernel<85, 88><<<(N + 3) / 4, 256, 0, stream>>>(rowptr, csr, pbuf, bufA, N);

    // Layer 1: 85 -> 56 (in stride 88, out stride 56)
    proj_kernel<88, 88, 56, 56, 64, 128><<<rowTiles, 256, 0, stream>>>(
        bufA, Wc1, bl[1], pbuf, bufB, N);
    gather_kernel<56, 56><<<(N + 3) / 4, 256, 0, stream>>>(rowptr, csr, pbuf, bufB, N);

    // Layer 2: 56 -> 28 (in stride 56, out stride 28)
    proj_kernel<56, 56, 28, 28, 32, 64><<<rowTiles, 256, 0, stream>>>(
        bufB, Wc2, bl[2], pbuf, bufA, N);
    gather_kernel<28, 28><<<(N + 3) / 4, 256, 0, stream>>>(rowptr, csr, pbuf, bufA, N);

    // Layer 3: 28 -> 1 (in stride 28)
    gemv3_kernel<<<(N + 255) / 256, 256, 0, stream>>>(
        bufA, Wl[3], bl[3], Wr[3], pbuf, (float*)d_out, N);
    gather1_kernel<<<(N + 255) / 256, 256, 0, stream>>>(
        rowptr, csr, pbuf, (float*)d_out, N);
}